// Round 1
// baseline (234.546 us; speedup 1.0000x reference)
//
#include <hip/hip_runtime.h>

#define NB 16384
#define NC 1000
#define NF 256

typedef _Float16 half8 __attribute__((ext_vector_type(8)));
typedef _Float16 half4v __attribute__((ext_vector_type(4)));
typedef float f32x4 __attribute__((ext_vector_type(4)));

// ---- prep: means fp32->fp16, m2[c] = ||m_c||^2 (exact fp32), inv_scale ----
__global__ __launch_bounds__(256) void prep_means_kernel(
    const float* __restrict__ mean_vecs,
    const float* __restrict__ wb_scale,
    _Float16* __restrict__ m16,
    float* __restrict__ m2,
    float* __restrict__ inv_scale)
{
    const int wave = threadIdx.x >> 6;
    const int lane = threadIdx.x & 63;
    const int r = blockIdx.x * 4 + wave;          // grid=250 -> rows 0..999
    const float4* src = (const float4*)(mean_vecs + (size_t)r * NF);
    float4 v = src[lane];
    half4v h;
    h[0] = (_Float16)v.x; h[1] = (_Float16)v.y;
    h[2] = (_Float16)v.z; h[3] = (_Float16)v.w;
    *(half4v*)(m16 + (size_t)r * NF + lane * 4) = h;
    float s = v.x*v.x + v.y*v.y + v.z*v.z + v.w*v.w;
    #pragma unroll
    for (int off = 1; off < 64; off <<= 1) s += __shfl_xor(s, off, 64);
    if (lane == 0) { m2[r] = s; inv_scale[r] = 1.0f / wb_scale[r]; }
}

// ---- main: fused distance-GEMM (fp16 MFMA) + Weibull + softmax ----
// block = 128 threads = 2 waves; each wave: 16 rows x all 1000 classes.
__global__ __launch_bounds__(128) void openmax_kernel(
    const float* __restrict__ logits,
    const float* __restrict__ features,
    const float* __restrict__ wb_shape,
    const float* __restrict__ wb_loc,
    const _Float16* __restrict__ m16,
    const float* __restrict__ m2,
    const float* __restrict__ inv_scale,
    float* __restrict__ out)
{
    __shared__ _Float16 esm[2][16][NC];   // 64000 B, per-wave private halves

    const int wave = threadIdx.x >> 6;
    const int lane = threadIdx.x & 63;
    const int q    = lane >> 4;           // 0..3
    const int mr   = lane & 15;           // 0..15
    const int row0 = blockIdx.x * 32 + wave * 16;

    // A fragments: lane holds A[m=lane&15][k = q*8 + j + 32*kk], fp32->fp16.
    // f2 computed from exact fp32 values before conversion.
    half8 afrag[8];
    float f2 = 0.f;
    const float* fbase = features + (size_t)(row0 + mr) * NF;
    #pragma unroll
    for (int kk = 0; kk < 8; ++kk) {
        const float4* p = (const float4*)(fbase + kk * 32 + q * 8);
        float4 lo = p[0], hi = p[1];
        f2 += lo.x*lo.x + lo.y*lo.y + lo.z*lo.z + lo.w*lo.w
            + hi.x*hi.x + hi.y*hi.y + hi.z*hi.z + hi.w*hi.w;
        half8 a;
        a[0]=(_Float16)lo.x; a[1]=(_Float16)lo.y; a[2]=(_Float16)lo.z; a[3]=(_Float16)lo.w;
        a[4]=(_Float16)hi.x; a[5]=(_Float16)hi.y; a[6]=(_Float16)hi.z; a[7]=(_Float16)hi.w;
        afrag[kk] = a;
    }
    // reduce over k-quads (lanes differing in bits 4..5 share the same row)
    f2 += __shfl_xor(f2, 16, 64);
    f2 += __shfl_xor(f2, 32, 64);
    // redistribute: epilogue lane needs f2 of rows q*4+r
    float f2r[4];
    #pragma unroll
    for (int r = 0; r < 4; ++r) f2r[r] = __shfl(f2, q * 4 + r, 64);

    const float LOG2E = 1.44269504088896340736f;
    float rsum[4] = {0.f, 0.f, 0.f, 0.f};

    for (int ct = 0; ct < 63; ++ct) {
        const int c0 = ct * 16;
        const int c  = c0 + mr;
        const bool cv = (c < NC);
        const int cc = cv ? c : (NC - 1);

        // B fragments straight from global (L1/L2 resident fp16 means)
        const _Float16* mb = m16 + (size_t)cc * NF;
        half8 bfrag[8];
        #pragma unroll
        for (int kk = 0; kk < 8; ++kk)
            bfrag[kk] = *(const half8*)(mb + kk * 32 + q * 8);

        // per-class params + logits issued before MFMA so latency overlaps
        float m2c = m2[cc];
        float shp = wb_shape[cc];
        float loc = wb_loc[cc];
        float isc = inv_scale[cc];
        float lg[4];
        #pragma unroll
        for (int r = 0; r < 4; ++r)
            lg[r] = logits[(size_t)(row0 + q * 4 + r) * NC + cc];

        f32x4 acc = {0.f, 0.f, 0.f, 0.f};
        #pragma unroll
        for (int kk = 0; kk < 8; ++kk)
            acc = __builtin_amdgcn_mfma_f32_16x16x32_f16(afrag[kk], bfrag[kk], acc, 0, 0, 0);

        // epilogue: D[row=q*4+r][col=mr]
        #pragma unroll
        for (int r = 0; r < 4; ++r) {
            float d2   = fmaxf(f2r[r] + m2c - 2.0f * acc[r], 1e-12f);
            float dist = sqrtf(d2);
            float xp   = (dist - loc) * isc;
            float xs   = fmaxf(xp, 1e-30f);
            float t    = exp2f(shp * log2f(xs));        // xp^shape
            float w    = 1.0f - exp2f(-t * LOG2E);      // weibull CDF
            w = (xp > 0.f) ? w : 0.f;
            float w2 = w * w, w4 = w2 * w2, w8 = w4 * w4;
            float s  = lg[r] * (1.0f - w8 * w2);        // 1 - w^10
            float e  = cv ? exp2f(s * LOG2E) : 0.f;     // exp(s), |s|<~6 safe
            rsum[r] += e;
            if (cv) esm[wave][q * 4 + r][c] = (_Float16)e;
        }
    }

    // row sums live across the 16 lanes sharing a q-group (bits 0..3)
    #pragma unroll
    for (int r = 0; r < 4; ++r) {
        float v = rsum[r];
        v += __shfl_xor(v, 1, 64);
        v += __shfl_xor(v, 2, 64);
        v += __shfl_xor(v, 4, 64);
        v += __shfl_xor(v, 8, 64);
        rsum[r] = 1.0f / v;
    }

    // normalize + store
    for (int ct = 0; ct < 63; ++ct) {
        const int c = ct * 16 + mr;
        if (c < NC) {
            #pragma unroll
            for (int r = 0; r < 4; ++r)
                out[(size_t)(row0 + q * 4 + r) * NC + c] =
                    (float)esm[wave][q * 4 + r][c] * rsum[r];
        }
    }
}

extern "C" void kernel_launch(void* const* d_in, const int* in_sizes, int n_in,
                              void* d_out, int out_size, void* d_ws, size_t ws_size,
                              hipStream_t stream) {
    const float* logits    = (const float*)d_in[0];
    const float* features  = (const float*)d_in[1];
    const float* mean_vecs = (const float*)d_in[2];
    const float* wb_shape  = (const float*)d_in[3];
    const float* wb_loc    = (const float*)d_in[4];
    const float* wb_scale  = (const float*)d_in[5];
    float* out = (float*)d_out;

    _Float16* m16  = (_Float16*)d_ws;                    // 512000 B
    float* m2      = (float*)((char*)d_ws + 512000);     // 4000 B
    float* invs    = (float*)((char*)d_ws + 516000);     // 4000 B

    prep_means_kernel<<<250, 256, 0, stream>>>(mean_vecs, wb_scale, m16, m2, invs);
    openmax_kernel<<<NB / 32, 128, 0, stream>>>(logits, features, wb_shape, wb_loc,
                                                m16, m2, invs, out);
}

// Round 2
// 203.775 us; speedup vs baseline: 1.1510x; 1.1510x over previous
//
#include <hip/hip_runtime.h>

#define NB 16384
#define NC 1000
#define NF 256

typedef _Float16 half8 __attribute__((ext_vector_type(8)));
typedef _Float16 half4v __attribute__((ext_vector_type(4)));
typedef float f32x4 __attribute__((ext_vector_type(4)));

// ---- prep: means fp32->fp16; pack per-class params {m2, shape, loc, 1/scale} ----
__global__ __launch_bounds__(256) void prep_means_kernel(
    const float* __restrict__ mean_vecs,
    const float* __restrict__ wb_shape,
    const float* __restrict__ wb_loc,
    const float* __restrict__ wb_scale,
    _Float16* __restrict__ m16,
    float4* __restrict__ params)
{
    const int wave = threadIdx.x >> 6;
    const int lane = threadIdx.x & 63;
    const int r = blockIdx.x * 4 + wave;          // grid=250 -> rows 0..999
    const float4* src = (const float4*)(mean_vecs + (size_t)r * NF);
    float4 v = src[lane];
    half4v h;
    h[0] = (_Float16)v.x; h[1] = (_Float16)v.y;
    h[2] = (_Float16)v.z; h[3] = (_Float16)v.w;
    *(half4v*)(m16 + (size_t)r * NF + lane * 4) = h;
    float s = v.x*v.x + v.y*v.y + v.z*v.z + v.w*v.w;
    #pragma unroll
    for (int off = 1; off < 64; off <<= 1) s += __shfl_xor(s, off, 64);
    if (lane == 0) {
        float4 p;
        p.x = s;                  // ||m_c||^2 (exact fp32)
        p.y = wb_shape[r];
        p.z = wb_loc[r];
        p.w = 1.0f / wb_scale[r];
        params[r] = p;
    }
}

// ---- main: fused distance-GEMM (fp16 MFMA) + Weibull + softmax ----
// block = 512 threads = 8 waves, all sharing rows [row0, row0+16).
// Wave w owns class-tiles w*8 .. w*8+7 (128 class slots); e-values kept in
// registers (packed fp16), so LDS is only the 512 B cross-wave partial array.
__global__ __launch_bounds__(512, 4) void openmax_kernel(
    const float* __restrict__ logits,
    const float* __restrict__ features,
    const _Float16* __restrict__ m16,
    const float4* __restrict__ params,
    float* __restrict__ out)
{
    __shared__ float part[16][8];         // [row][wave] partial softmax sums

    const int wave = threadIdx.x >> 6;
    const int lane = threadIdx.x & 63;
    const int q    = lane >> 4;           // 0..3
    const int mr   = lane & 15;           // 0..15
    const int row0 = blockIdx.x * 16;

    // A fragments: lane holds A[m=lane&15][k = q*8 + j + 32*kk], fp32->fp16.
    // f2 computed from exact fp32 values before conversion.
    half8 afrag[8];
    float f2 = 0.f;
    const float* fbase = features + (size_t)(row0 + mr) * NF;
    #pragma unroll
    for (int kk = 0; kk < 8; ++kk) {
        const float4* p = (const float4*)(fbase + kk * 32 + q * 8);
        float4 lo = p[0], hi = p[1];
        f2 += lo.x*lo.x + lo.y*lo.y + lo.z*lo.z + lo.w*lo.w
            + hi.x*hi.x + hi.y*hi.y + hi.z*hi.z + hi.w*hi.w;
        half8 a;
        a[0]=(_Float16)lo.x; a[1]=(_Float16)lo.y; a[2]=(_Float16)lo.z; a[3]=(_Float16)lo.w;
        a[4]=(_Float16)hi.x; a[5]=(_Float16)hi.y; a[6]=(_Float16)hi.z; a[7]=(_Float16)hi.w;
        afrag[kk] = a;
    }
    f2 += __shfl_xor(f2, 16, 64);
    f2 += __shfl_xor(f2, 32, 64);
    float f2r[4];
    #pragma unroll
    for (int r = 0; r < 4; ++r) f2r[r] = __shfl(f2, q * 4 + r, 64);

    const float LOG2E = 1.44269504088896340736f;
    float rsum[4] = {0.f, 0.f, 0.f, 0.f};
    half4v ehold[8];                      // e-values, 4 rows x 8 tiles, fp16

    #pragma unroll
    for (int i = 0; i < 8; ++i) {
        const int ct = wave * 8 + i;
        const int c  = ct * 16 + mr;
        const bool cv = (c < NC);
        const int cc = cv ? c : (NC - 1);

        // B fragments straight from global (L1/L2-resident fp16 means)
        const _Float16* mb = m16 + (size_t)cc * NF;
        half8 bfrag[8];
        #pragma unroll
        for (int kk = 0; kk < 8; ++kk)
            bfrag[kk] = *(const half8*)(mb + kk * 32 + q * 8);

        const float4 prm = params[cc];    // {m2, shape, loc, 1/scale}
        float lg[4];
        #pragma unroll
        for (int r = 0; r < 4; ++r)
            lg[r] = logits[(size_t)(row0 + q * 4 + r) * NC + cc];

        f32x4 acc = {0.f, 0.f, 0.f, 0.f};
        #pragma unroll
        for (int kk = 0; kk < 8; ++kk)
            acc = __builtin_amdgcn_mfma_f32_16x16x32_f16(afrag[kk], bfrag[kk], acc, 0, 0, 0);

        // epilogue: D[row=q*4+r][col=mr]
        #pragma unroll
        for (int r = 0; r < 4; ++r) {
            float d2   = fmaxf(f2r[r] + prm.x - 2.0f * acc[r], 1e-12f);
            float dist = sqrtf(d2);
            float xp   = (dist - prm.z) * prm.w;
            float xs   = fmaxf(xp, 1e-30f);
            float t    = exp2f(prm.y * log2f(xs));       // xp^shape
            float w    = (xp > 0.f) ? (1.0f - exp2f(-t * LOG2E)) : 0.f;
            float w2 = w * w, w4 = w2 * w2, w8 = w4 * w4;
            float s  = lg[r] * (1.0f - w8 * w2);         // 1 - w^10
            float e  = cv ? exp2f(s * LOG2E) : 0.f;      // exp(s), |s|<~6 safe
            rsum[r] += e;
            ehold[i][r] = (_Float16)e;
        }
    }

    // intra-wave: sum over the 16 lanes of each q-group -> per-row partial
    #pragma unroll
    for (int r = 0; r < 4; ++r) {
        float v = rsum[r];
        v += __shfl_xor(v, 1, 64);
        v += __shfl_xor(v, 2, 64);
        v += __shfl_xor(v, 4, 64);
        v += __shfl_xor(v, 8, 64);
        if (mr == r) part[q * 4 + r][wave] = v;
    }
    __syncthreads();

    // cross-wave: total per row, then invert
    float inv[4];
    #pragma unroll
    for (int r = 0; r < 4; ++r) {
        const float4* p4 = (const float4*)part[q * 4 + r];
        float4 a = p4[0], b = p4[1];
        inv[r] = 1.0f / (a.x + a.y + a.z + a.w + b.x + b.y + b.z + b.w);
    }

    // normalize from registers + store
    #pragma unroll
    for (int i = 0; i < 8; ++i) {
        const int c = wave * 128 + i * 16 + mr;
        if (c < NC) {
            #pragma unroll
            for (int r = 0; r < 4; ++r)
                out[(size_t)(row0 + q * 4 + r) * NC + c] = (float)ehold[i][r] * inv[r];
        }
    }
}

extern "C" void kernel_launch(void* const* d_in, const int* in_sizes, int n_in,
                              void* d_out, int out_size, void* d_ws, size_t ws_size,
                              hipStream_t stream) {
    const float* logits    = (const float*)d_in[0];
    const float* features  = (const float*)d_in[1];
    const float* mean_vecs = (const float*)d_in[2];
    const float* wb_shape  = (const float*)d_in[3];
    const float* wb_loc    = (const float*)d_in[4];
    const float* wb_scale  = (const float*)d_in[5];
    float* out = (float*)d_out;

    _Float16* m16  = (_Float16*)d_ws;                    // 512000 B
    float4* params = (float4*)((char*)d_ws + 512000);    // 16000 B

    prep_means_kernel<<<250, 256, 0, stream>>>(mean_vecs, wb_shape, wb_loc, wb_scale,
                                               m16, params);
    openmax_kernel<<<NB / 16, 512, 0, stream>>>(logits, features, m16, params, out);
}